// Round 19
// baseline (220.196 us; speedup 1.0000x reference)
//
#include <hip/hip_runtime.h>
#include <hip/hip_bf16.h>

typedef __bf16 bf16;
typedef __bf16 bf16x8 __attribute__((ext_vector_type(8)));
typedef float f32x2 __attribute__((ext_vector_type(2)));
typedef float f32x4 __attribute__((ext_vector_type(4)));
typedef float f32x16 __attribute__((ext_vector_type(16)));
typedef short s16x4 __attribute__((ext_vector_type(4)));

#define GLDS16(gp, lp) __builtin_amdgcn_global_load_lds( \
    (const __attribute__((address_space(1))) void*)(gp), \
    (__attribute__((address_space(3))) void*)(lp), 16, 0, 0)

__device__ __forceinline__ bf16 f2bf(float f) {
    unsigned u = __builtin_bit_cast(unsigned, f);
    u = (u + 0x7FFFu + ((u >> 16) & 1u)) >> 16;
    unsigned short s = (unsigned short)u;
    return __builtin_bit_cast(bf16, s);
}
__device__ __forceinline__ void store_c(float* p, float v) { *p = v; }
__device__ __forceinline__ void store_c(bf16*  p, float v) { *p = f2bf(v); }

__device__ __forceinline__ float exp2_fast(float x) {
    float r; asm("v_exp_f32 %0, %1" : "=v"(r) : "v"(x)); return r;
}
__device__ __forceinline__ unsigned cvt_pk_bf16(float lo, float hi) {
    unsigned r;
    asm("v_cvt_pk_bf16_f32 %0, %1, %2" : "=v"(r) : "v"(lo), "v"(hi));
    return r;
}
__device__ __forceinline__ void permlane32_swap(unsigned &a, unsigned &b) {
    asm("v_permlane32_swap_b32 %0, %1" : "+v"(a), "+v"(b));
}
// addr = 32-bit DS offset of a VALID __shared__ pointer; asm operand only (R8).
__device__ __forceinline__ s16x4 ds_tr16(unsigned addr) {
    s16x4 d;
    asm volatile("ds_read_b64_tr_b16 %0, %1" : "=v"(d) : "v"(addr));
    return d;
}

// ---- fp32 -> bf16 bulk convert, two segments in one launch ----
__global__ __launch_bounds__(256) void cvt2_f32_bf16(
    const float* __restrict__ inA, bf16* __restrict__ outA, int nA8,
    const float* __restrict__ inB, bf16* __restrict__ outB, int nB8)
{
    int i = blockIdx.x * 256 + threadIdx.x;
    const float* in; bf16* out;
    if (i < nA8) { in = inA; out = outA; }
    else         { i -= nA8; if (i >= nB8) return; in = inB; out = outB; }
    f32x4 a = *(const f32x4*)(in + (size_t)i * 8);
    f32x4 b = *(const f32x4*)(in + (size_t)i * 8 + 4);
    bf16x8 o;
    #pragma unroll
    for (int j = 0; j < 4; ++j) { o[j] = f2bf(a[j]); o[4 + j] = f2bf(b[j]); }
    *(bf16x8*)(out + (size_t)i * 8) = o;
}
__global__ __launch_bounds__(256) void cvt_f32_bf16(
    const float* __restrict__ in, bf16* __restrict__ out, int n8)
{
    int i = blockIdx.x * 256 + threadIdx.x;
    if (i >= n8) return;
    f32x4 a = *(const f32x4*)(in + (size_t)i * 8);
    f32x4 b = *(const f32x4*)(in + (size_t)i * 8 + 4);
    bf16x8 o;
    #pragma unroll
    for (int j = 0; j < 4; ++j) { o[j] = f2bf(a[j]); o[4 + j] = f2bf(b[j]); }
    *(bf16x8*)(out + (size_t)i * 8) = o;
}

// ---------------------------------------------------------------------------
// Pipelined m97-layout GEMM (R13 structure) + R19 XCD column-group swizzle:
// 1-D grid, XCD c owns x-blocks [c*xpc, (c+1)*xpc) -> per-XCD B working set
// (0.75MB gemm1 / 256KB gemm2) stays L2-resident across all 64 row-iters,
// shortening the vmcnt wait the pipeline stalls on. Bijective (nbx%8==0).
// ---------------------------------------------------------------------------
template <typename TC>
__global__ __launch_bounds__(256) void gemm_pipe(
    const bf16* __restrict__ A, const bf16* __restrict__ B, TC* __restrict__ C,
    int M, int N, int K)
{
    __shared__ alignas(16) bf16 As[3][128 * 32];
    __shared__ alignas(16) bf16 Bs[3][32 * 128];

    const int tid  = threadIdx.x;
    const int wv   = tid >> 6;
    const int lane = tid & 63;
    const int lr   = lane & 15;
    const int kb   = lane >> 4;
    const int wr   = wv >> 1, wc = wv & 1;

    // XCD swizzle: dispatch round-robins id%8 across XCDs; give XCD c a
    // contiguous column group so its B slice is private-L2-resident.
    const int id  = (int)blockIdx.x;
    const int nbx = N >> 7;            // 24 (gemm1) or 8 (gemm2); %8==0
    const int xpc = nbx >> 3;
    const int c_  = id & 7, j_ = id >> 3;
    const int bx  = c_ * xpc + j_ % xpc;
    const int by  = j_ / xpc;
    const int brow = by * 128;
    const int bcol = bx * 128;

    f32x4 acc[4][4] = {};

    const int ar0 = wv * 16 + (lane >> 2);
    const int ac0 = (lane & 3) * 8;

    const int bL   = wv * 1024 + lane * 16;
    const int bs0  = bL >> 7;
    const int b_r  = (bL & 127) >> 5;
    const int b_c0 = (bL & 31) >> 1;

    auto stage = [&](int buf, int k0) {
        #pragma unroll
        for (int t = 0; t < 2; ++t)
            GLDS16(A + (size_t)(brow + t * 64 + ar0) * K + k0 + ac0,
                   &As[buf][t * 2048 + wv * 512]);
        #pragma unroll
        for (int t = 0; t < 2; ++t) {
            int s = bs0 + t * 32;
            GLDS16(B + (size_t)(k0 + (s >> 3) * 4 + b_r) * N + bcol + (s & 7) * 16 + b_c0,
                   &Bs[buf][t * 2048 + wv * 512]);
        }
    };

    stage(0, 0);
    stage(1, 32);

    const int KT = K >> 5;
    for (int kt = 0; kt < KT; ++kt) {
        if (kt + 1 < KT) asm volatile("s_waitcnt vmcnt(4)" ::: "memory");
        else             asm volatile("s_waitcnt vmcnt(0)" ::: "memory");
        __builtin_amdgcn_s_barrier();
        __builtin_amdgcn_sched_barrier(0);

        if (kt + 2 < KT) stage((kt + 2) % 3, (kt + 2) << 5);

        const int cur = kt % 3;
        const bf16* Ab = As[cur];
        bf16x8 af[4], bfr[4];
        #pragma unroll
        for (int m = 0; m < 4; ++m)
            af[m] = *(const bf16x8*)&Ab[(wr * 64 + m * 16 + lr) * 32 + kb * 8];
        {
            s16x4 tr[8];
            const unsigned bsb = (unsigned)(uintptr_t)Bs[cur] + kb * 2048 + lr * 8;
            #pragma unroll
            for (int nt = 0; nt < 4; ++nt) {
                unsigned a = bsb + (wc * 4 + nt) * 128;
                tr[nt * 2]     = ds_tr16(a);
                tr[nt * 2 + 1] = ds_tr16(a + 1024);
            }
            asm volatile("s_waitcnt lgkmcnt(0)" ::: "memory");
            __builtin_amdgcn_sched_barrier(0);
            #pragma unroll
            for (int nt = 0; nt < 4; ++nt) {
                union { bf16x8 f; s16x4 h[2]; } u;
                u.h[0] = tr[nt * 2]; u.h[1] = tr[nt * 2 + 1];
                bfr[nt] = u.f;
            }
        }
        __builtin_amdgcn_s_setprio(1);
        #pragma unroll
        for (int m = 0; m < 4; ++m)
            #pragma unroll
            for (int n = 0; n < 4; ++n)
                acc[m][n] = __builtin_amdgcn_mfma_f32_16x16x32_bf16(af[m], bfr[n], acc[m][n], 0, 0, 0);
        __builtin_amdgcn_s_setprio(0);
    }

    #pragma unroll
    for (int m = 0; m < 4; ++m)
        #pragma unroll
        for (int n = 0; n < 4; ++n)
            #pragma unroll
            for (int r = 0; r < 4; ++r) {
                int row = brow + wr * 64 + m * 16 + kb * 4 + r;   // verified C-layout
                int col = bcol + wc * 64 + n * 16 + lr;
                store_c(&C[(size_t)row * N + col], acc[m][n][r]);
            }
}

// ---------------------------------------------------------------------------
// MFMA-32x32 flash attention (FROZEN — ~114us; VGPR=92 rounds to 128 ->
// hard cap 4 waves/SIMD; serial VALU chain pinned; all variants A/B'd).
// ---------------------------------------------------------------------------
__global__ __launch_bounds__(256) void attn_mfma32(
    const bf16* __restrict__ qkv, bf16* __restrict__ attn_out)
{
    constexpr int NSEQ = 2048, DM = 1024, LD = 3072, KVB = 64, QB = 128;
    constexpr int NT = NSEQ / KVB;
    constexpr float THR = 11.5f;
    __shared__ alignas(16) bf16 KsBuf[2][64][72];
    __shared__ alignas(16) bf16 VsBuf[2][4096];

    const int tid = threadIdx.x;
    const int wv = tid >> 6, lane = tid & 63;
    const int l31 = lane & 31;
    const int hi_ = lane >> 5;
    const int g16 = (lane >> 4) & 1;
    const int l16 = lane & 15;

    const int q0 = blockIdx.x * QB;
    const int bh = blockIdx.y;
    const int b = bh >> 4, h = bh & 15;

    const bf16* qbase = qkv + (size_t)(b * NSEQ) * LD + h * 64;
    const bf16* kbase = qbase + DM;
    const bf16* vbase = qbase + 2 * DM;

    bf16x8 qf[4];
    {
        const float QSC = 0.125f * 1.44269504f;
        const bf16* qp = qbase + (size_t)(q0 + wv * 32 + l31) * LD + hi_ * 8;
        #pragma unroll
        for (int ds = 0; ds < 4; ++ds) {
            bf16x8 t = *(const bf16x8*)(qp + ds * 16);
            #pragma unroll
            for (int e = 0; e < 8; ++e) t[e] = f2bf((float)t[e] * QSC);
            qf[ds] = t;
        }
    }

    f32x16 o0 = {}, o1 = {};
    float mrow = -INFINITY, lsum = 0.f;

    const int krow = tid >> 2, kcol = (tid & 3) * 16;

    auto vload = [&](int j0, int L) {
        int kq = L >> 8, cb = (L >> 6) & 3, rr = (L >> 4) & 3, c0 = L & 15;
        return *(const bf16x8*)(vbase + (size_t)(j0 + kq * 4 + rr) * LD + cb * 16 + c0);
    };

    bf16x8 kr0 = *(const bf16x8*)(kbase + (size_t)krow * LD + kcol);
    bf16x8 kr1 = *(const bf16x8*)(kbase + (size_t)krow * LD + kcol + 8);
    bf16x8 vr0 = vload(0, tid * 8);
    bf16x8 vr1 = vload(0, 2048 + tid * 8);

    for (int kt = 0; kt < NT; ++kt) {
        const int cur = kt & 1;
        bf16 (*Ks)[72] = KsBuf[cur];
        bf16 *Vs       = VsBuf[cur];
        const unsigned vb = (unsigned)(uintptr_t)Vs;

        *(bf16x8*)&Ks[krow][kcol]       = kr0;
        *(bf16x8*)&Ks[krow][kcol + 8]   = kr1;
        *(bf16x8*)(Vs + tid * 8)        = vr0;
        *(bf16x8*)(Vs + 2048 + tid * 8) = vr1;
        __syncthreads();

        {
            const int jn = (kt + 1 < NT ? kt + 1 : kt) * KVB;
            kr0 = *(const bf16x8*)(kbase + (size_t)(jn + krow) * LD + kcol);
            kr1 = *(const bf16x8*)(kbase + (size_t)(jn + krow) * LD + kcol + 8);
            vr0 = vload(jn, tid * 8);
            vr1 = vload(jn, 2048 + tid * 8);
        }

        f32x16 sT0 = {}, sT1 = {};
        __builtin_amdgcn_s_setprio(1);
        #pragma unroll
        for (int ds = 0; ds < 4; ++ds) {
            bf16x8 kf = *(const bf16x8*)&Ks[l31][ds * 16 + hi_ * 8];
            sT0 = __builtin_amdgcn_mfma_f32_32x32x16_bf16(kf, qf[ds], sT0, 0, 0, 0);
        }
        #pragma unroll
        for (int ds = 0; ds < 4; ++ds) {
            bf16x8 kf = *(const bf16x8*)&Ks[32 + l31][ds * 16 + hi_ * 8];
            sT1 = __builtin_amdgcn_mfma_f32_32x32x16_bf16(kf, qf[ds], sT1, 0, 0, 0);
        }
        __builtin_amdgcn_s_setprio(0);

        float pm = fmaxf(sT0[0], sT0[1]);
        #pragma unroll
        for (int r = 2; r < 16; r += 2) pm = fmaxf(fmaxf(pm, sT0[r]), sT0[r + 1]);
        #pragma unroll
        for (int r = 0; r < 16; r += 2) pm = fmaxf(fmaxf(pm, sT1[r]), sT1[r + 1]);
        pm = fmaxf(pm, __shfl_xor(pm, 32));
        if (!__all(pm <= mrow + THR)) {
            const float mn = fmaxf(mrow, pm);
            const float corr = exp2_fast(mrow - mn);
            mrow = mn;
            lsum *= corr;
            #pragma unroll
            for (int r = 0; r < 16; ++r) { o0[r] *= corr; o1[r] *= corr; }
        }
        #pragma unroll
        for (int r = 0; r < 16; ++r) sT0[r] = exp2_fast(sT0[r] - mrow);
        #pragma unroll
        for (int r = 0; r < 16; ++r) sT1[r] = exp2_fast(sT1[r] - mrow);
        f32x2 ps2 = {0.f, 0.f};
        #pragma unroll
        for (int r = 0; r < 16; r += 2) {
            ps2 += (f32x2){sT0[r], sT0[r + 1]};
            ps2 += (f32x2){sT1[r], sT1[r + 1]};
        }
        float ps = ps2[0] + ps2[1];
        ps += __shfl_xor(ps, 32);
        lsum += ps;

        unsigned w0[8], w1[8];
        #pragma unroll
        for (int j2 = 0; j2 < 8; ++j2) {
            w0[j2] = cvt_pk_bf16(sT0[2 * j2], sT0[2 * j2 + 1]);
            w1[j2] = cvt_pk_bf16(sT1[2 * j2], sT1[2 * j2 + 1]);
        }
        bf16x8 pf[4];
        #pragma unroll
        for (int ks = 0; ks < 4; ++ks) {
            const int jb = 4 * (ks & 1);
            unsigned a0 = (ks >> 1) ? w1[jb]     : w0[jb];
            unsigned b0 = (ks >> 1) ? w1[jb + 2] : w0[jb + 2];
            unsigned a1 = (ks >> 1) ? w1[jb + 1] : w0[jb + 1];
            unsigned b1 = (ks >> 1) ? w1[jb + 3] : w0[jb + 3];
            permlane32_swap(a0, b0);
            permlane32_swap(a1, b1);
            union { bf16x8 f; unsigned w[4]; } u;
            u.w[0] = a0; u.w[1] = a1; u.w[2] = b0; u.w[3] = b1;
            pf[ks] = u.f;
        }

        #pragma unroll
        for (int dt = 0; dt < 2; ++dt) {
            s16x4 t[8];
            #pragma unroll
            for (int ks = 0; ks < 4; ++ks) {
                unsigned a = vb + ks * 2048 + hi_ * 1024 + dt * 256 + g16 * 128 + l16 * 8;
                t[ks * 2]     = ds_tr16(a);
                t[ks * 2 + 1] = ds_tr16(a + 512);
            }
            asm volatile("s_waitcnt lgkmcnt(0)" ::: "memory");
            __builtin_amdgcn_sched_barrier(0);
            __builtin_amdgcn_s_setprio(1);
            #pragma unroll
            for (int ks = 0; ks < 4; ++ks) {
                union { bf16x8 f; s16x4 h[2]; } u;
                u.h[0] = t[ks * 2]; u.h[1] = t[ks * 2 + 1];
                if (dt == 0) o0 = __builtin_amdgcn_mfma_f32_32x32x16_bf16(u.f, pf[ks], o0, 0, 0, 0);
                else         o1 = __builtin_amdgcn_mfma_f32_32x32x16_bf16(u.f, pf[ks], o1, 0, 0, 0);
            }
            __builtin_amdgcn_s_setprio(0);
        }
    }

    bf16 (*Os)[72] = (bf16 (*)[72])&KsBuf[0][0][0];
    const float inv = 1.f / lsum;
    __syncthreads();
    #pragma unroll
    for (int r = 0; r < 16; ++r) {
        const int d0 = (r & 3) + 8 * (r >> 2) + 4 * hi_;
        Os[wv * 32 + l31][d0]      = f2bf(o0[r] * inv);
        Os[wv * 32 + l31][32 + d0] = f2bf(o1[r] * inv);
    }
    __syncthreads();
    {
        const int row = tid >> 1, c0 = (tid & 1) * 32;
        bf16* op = attn_out + (size_t)(b * NSEQ + q0 + row) * DM + h * 64 + c0;
        #pragma unroll
        for (int e = 0; e < 4; ++e)
            *(bf16x8*)(op + e * 8) = *(const bf16x8*)&Os[row][c0 + e * 8];
    }
}

extern "C" void kernel_launch(void* const* d_in, const int* in_sizes, int n_in,
                              void* d_out, int out_size, void* d_ws, size_t ws_size,
                              hipStream_t stream) {
    const float* x     = (const float*)d_in[0];   // [4,2048,1024] fp32
    const float* w_qkv = (const float*)d_in[1];   // [1024,3072]  fp32
    const float* w_out = (const float*)d_in[2];   // [1024,1024]  fp32
    float* out = (float*)d_out;                   // [4,2048,1024] fp32

    bf16* x_bf    = (bf16*)d_out;                 // scratch in d_out
    bf16* qkv     = (bf16*)d_ws;                  // ws[0,48MiB)
    bf16* wqkv_bf = qkv + (size_t)8192 * 3072;    // ws[48,54MiB)
    bf16* attnb   = wqkv_bf;                      // reuse after gemm1
    bf16* wo_bf   = (bf16*)d_ws;                  // reuse after attn

    cvt2_f32_bf16<<<4096 + 1536, 256, 0, stream>>>(
        x, x_bf, 8192 * 1024 / 8, w_qkv, wqkv_bf, 1024 * 3072 / 8);
    gemm_pipe<bf16><<<(3072 / 128) * (8192 / 128), 256, 0, stream>>>(
        x_bf, wqkv_bf, qkv, 8192, 3072, 1024);
    attn_mfma32<<<dim3(2048 / 128, 64), 256, 0, stream>>>(qkv, attnb);
    cvt_f32_bf16<<<512, 256, 0, stream>>>(w_out, wo_bf, 1024 * 1024 / 8);
    gemm_pipe<float><<<(1024 / 128) * (8192 / 128), 256, 0, stream>>>(
        attnb, wo_bf, out, 8192, 1024, 1024);
}

// Round 20
// 217.867 us; speedup vs baseline: 1.0107x; 1.0107x over previous
//
#include <hip/hip_runtime.h>
#include <hip/hip_bf16.h>

typedef __bf16 bf16;
typedef __bf16 bf16x8 __attribute__((ext_vector_type(8)));
typedef float f32x2 __attribute__((ext_vector_type(2)));
typedef float f32x4 __attribute__((ext_vector_type(4)));
typedef float f32x16 __attribute__((ext_vector_type(16)));
typedef short s16x4 __attribute__((ext_vector_type(4)));

#define GLDS16(gp, lp) __builtin_amdgcn_global_load_lds( \
    (const __attribute__((address_space(1))) void*)(gp), \
    (__attribute__((address_space(3))) void*)(lp), 16, 0, 0)

__device__ __forceinline__ bf16 f2bf(float f) {
    unsigned u = __builtin_bit_cast(unsigned, f);
    u = (u + 0x7FFFu + ((u >> 16) & 1u)) >> 16;
    unsigned short s = (unsigned short)u;
    return __builtin_bit_cast(bf16, s);
}
__device__ __forceinline__ void store_c(float* p, float v) { *p = v; }
__device__ __forceinline__ void store_c(bf16*  p, float v) { *p = f2bf(v); }

__device__ __forceinline__ float exp2_fast(float x) {
    float r; asm("v_exp_f32 %0, %1" : "=v"(r) : "v"(x)); return r;
}
__device__ __forceinline__ unsigned cvt_pk_bf16(float lo, float hi) {
    unsigned r;
    asm("v_cvt_pk_bf16_f32 %0, %1, %2" : "=v"(r) : "v"(lo), "v"(hi));
    return r;
}
__device__ __forceinline__ void permlane32_swap(unsigned &a, unsigned &b) {
    asm("v_permlane32_swap_b32 %0, %1" : "+v"(a), "+v"(b));
}
// addr = 32-bit DS offset of a VALID __shared__ pointer; asm operand only (R8).
__device__ __forceinline__ s16x4 ds_tr16(unsigned addr) {
    s16x4 d;
    asm volatile("ds_read_b64_tr_b16 %0, %1" : "=v"(d) : "v"(addr));
    return d;
}

// ---- fp32 -> bf16 bulk convert, two segments in one launch ----
__global__ __launch_bounds__(256) void cvt2_f32_bf16(
    const float* __restrict__ inA, bf16* __restrict__ outA, int nA8,
    const float* __restrict__ inB, bf16* __restrict__ outB, int nB8)
{
    int i = blockIdx.x * 256 + threadIdx.x;
    const float* in; bf16* out;
    if (i < nA8) { in = inA; out = outA; }
    else         { i -= nA8; if (i >= nB8) return; in = inB; out = outB; }
    f32x4 a = *(const f32x4*)(in + (size_t)i * 8);
    f32x4 b = *(const f32x4*)(in + (size_t)i * 8 + 4);
    bf16x8 o;
    #pragma unroll
    for (int j = 0; j < 4; ++j) { o[j] = f2bf(a[j]); o[4 + j] = f2bf(b[j]); }
    *(bf16x8*)(out + (size_t)i * 8) = o;
}
__global__ __launch_bounds__(256) void cvt_f32_bf16(
    const float* __restrict__ in, bf16* __restrict__ out, int n8)
{
    int i = blockIdx.x * 256 + threadIdx.x;
    if (i >= n8) return;
    f32x4 a = *(const f32x4*)(in + (size_t)i * 8);
    f32x4 b = *(const f32x4*)(in + (size_t)i * 8 + 4);
    bf16x8 o;
    #pragma unroll
    for (int j = 0; j < 4; ++j) { o[j] = f2bf(a[j]); o[4 + j] = f2bf(b[j]); }
    *(bf16x8*)(out + (size_t)i * 8) = o;
}

// ---------------------------------------------------------------------------
// Pipelined m97-layout GEMM (R13, session best): 128x128, BK=32, 3 LDS
// buffers, counted vmcnt + raw s_barrier; one barrier/iter, no vmcnt(0) in
// loop. A/B history: 256-wide tiles (R17), n64 split (R16), 8-phase (R11),
// XCD swizzle (R19) all neutral or regress — this is the converged optimum
// for the 2-barrier structure class.
// ---------------------------------------------------------------------------
template <typename TC>
__global__ __launch_bounds__(256) void gemm_pipe(
    const bf16* __restrict__ A, const bf16* __restrict__ B, TC* __restrict__ C,
    int M, int N, int K)
{
    __shared__ alignas(16) bf16 As[3][128 * 32];
    __shared__ alignas(16) bf16 Bs[3][32 * 128];

    const int tid  = threadIdx.x;
    const int wv   = tid >> 6;
    const int lane = tid & 63;
    const int lr   = lane & 15;
    const int kb   = lane >> 4;
    const int wr   = wv >> 1, wc = wv & 1;
    const int brow = blockIdx.y * 128;
    const int bcol = blockIdx.x * 128;

    f32x4 acc[4][4] = {};

    const int ar0 = wv * 16 + (lane >> 2);
    const int ac0 = (lane & 3) * 8;

    const int bL   = wv * 1024 + lane * 16;
    const int bs0  = bL >> 7;
    const int b_r  = (bL & 127) >> 5;
    const int b_c0 = (bL & 31) >> 1;

    auto stage = [&](int buf, int k0) {
        #pragma unroll
        for (int t = 0; t < 2; ++t)
            GLDS16(A + (size_t)(brow + t * 64 + ar0) * K + k0 + ac0,
                   &As[buf][t * 2048 + wv * 512]);
        #pragma unroll
        for (int t = 0; t < 2; ++t) {
            int s = bs0 + t * 32;
            GLDS16(B + (size_t)(k0 + (s >> 3) * 4 + b_r) * N + bcol + (s & 7) * 16 + b_c0,
                   &Bs[buf][t * 2048 + wv * 512]);
        }
    };

    stage(0, 0);
    stage(1, 32);

    const int KT = K >> 5;
    for (int kt = 0; kt < KT; ++kt) {
        if (kt + 1 < KT) asm volatile("s_waitcnt vmcnt(4)" ::: "memory");
        else             asm volatile("s_waitcnt vmcnt(0)" ::: "memory");
        __builtin_amdgcn_s_barrier();
        __builtin_amdgcn_sched_barrier(0);

        if (kt + 2 < KT) stage((kt + 2) % 3, (kt + 2) << 5);

        const int cur = kt % 3;
        const bf16* Ab = As[cur];
        bf16x8 af[4], bfr[4];
        #pragma unroll
        for (int m = 0; m < 4; ++m)
            af[m] = *(const bf16x8*)&Ab[(wr * 64 + m * 16 + lr) * 32 + kb * 8];
        {
            s16x4 tr[8];
            const unsigned bsb = (unsigned)(uintptr_t)Bs[cur] + kb * 2048 + lr * 8;
            #pragma unroll
            for (int nt = 0; nt < 4; ++nt) {
                unsigned a = bsb + (wc * 4 + nt) * 128;
                tr[nt * 2]     = ds_tr16(a);
                tr[nt * 2 + 1] = ds_tr16(a + 1024);
            }
            asm volatile("s_waitcnt lgkmcnt(0)" ::: "memory");
            __builtin_amdgcn_sched_barrier(0);
            #pragma unroll
            for (int nt = 0; nt < 4; ++nt) {
                union { bf16x8 f; s16x4 h[2]; } u;
                u.h[0] = tr[nt * 2]; u.h[1] = tr[nt * 2 + 1];
                bfr[nt] = u.f;
            }
        }
        __builtin_amdgcn_s_setprio(1);
        #pragma unroll
        for (int m = 0; m < 4; ++m)
            #pragma unroll
            for (int n = 0; n < 4; ++n)
                acc[m][n] = __builtin_amdgcn_mfma_f32_16x16x32_bf16(af[m], bfr[n], acc[m][n], 0, 0, 0);
        __builtin_amdgcn_s_setprio(0);
    }

    #pragma unroll
    for (int m = 0; m < 4; ++m)
        #pragma unroll
        for (int n = 0; n < 4; ++n)
            #pragma unroll
            for (int r = 0; r < 4; ++r) {
                int row = brow + wr * 64 + m * 16 + kb * 4 + r;   // verified C-layout
                int col = bcol + wc * 64 + n * 16 + lr;
                store_c(&C[(size_t)row * N + col], acc[m][n][r]);
            }
}

// ---------------------------------------------------------------------------
// MFMA-32x32 flash attention (FROZEN — ~114.8us; VGPR=92 rounds to 128 ->
// hard cap 4 waves/SIMD (m69 quantization); serial VALU/exp chain pinned.
// 8 structural variants A/B'd: decode, barriers, buffers, swizzles, deferred
// PV — all neutral or worse. Breaking this needs the full T16 co-designed
// schedule, out of reach for safe headless one-shot rounds.)
// ---------------------------------------------------------------------------
__global__ __launch_bounds__(256) void attn_mfma32(
    const bf16* __restrict__ qkv, bf16* __restrict__ attn_out)
{
    constexpr int NSEQ = 2048, DM = 1024, LD = 3072, KVB = 64, QB = 128;
    constexpr int NT = NSEQ / KVB;
    constexpr float THR = 11.5f;
    __shared__ alignas(16) bf16 KsBuf[2][64][72];
    __shared__ alignas(16) bf16 VsBuf[2][4096];

    const int tid = threadIdx.x;
    const int wv = tid >> 6, lane = tid & 63;
    const int l31 = lane & 31;
    const int hi_ = lane >> 5;
    const int g16 = (lane >> 4) & 1;
    const int l16 = lane & 15;

    const int q0 = blockIdx.x * QB;
    const int bh = blockIdx.y;
    const int b = bh >> 4, h = bh & 15;

    const bf16* qbase = qkv + (size_t)(b * NSEQ) * LD + h * 64;
    const bf16* kbase = qbase + DM;
    const bf16* vbase = qbase + 2 * DM;

    bf16x8 qf[4];
    {
        const float QSC = 0.125f * 1.44269504f;
        const bf16* qp = qbase + (size_t)(q0 + wv * 32 + l31) * LD + hi_ * 8;
        #pragma unroll
        for (int ds = 0; ds < 4; ++ds) {
            bf16x8 t = *(const bf16x8*)(qp + ds * 16);
            #pragma unroll
            for (int e = 0; e < 8; ++e) t[e] = f2bf((float)t[e] * QSC);
            qf[ds] = t;
        }
    }

    f32x16 o0 = {}, o1 = {};
    float mrow = -INFINITY, lsum = 0.f;

    const int krow = tid >> 2, kcol = (tid & 3) * 16;

    auto vload = [&](int j0, int L) {
        int kq = L >> 8, cb = (L >> 6) & 3, rr = (L >> 4) & 3, c0 = L & 15;
        return *(const bf16x8*)(vbase + (size_t)(j0 + kq * 4 + rr) * LD + cb * 16 + c0);
    };

    bf16x8 kr0 = *(const bf16x8*)(kbase + (size_t)krow * LD + kcol);
    bf16x8 kr1 = *(const bf16x8*)(kbase + (size_t)krow * LD + kcol + 8);
    bf16x8 vr0 = vload(0, tid * 8);
    bf16x8 vr1 = vload(0, 2048 + tid * 8);

    for (int kt = 0; kt < NT; ++kt) {
        const int cur = kt & 1;
        bf16 (*Ks)[72] = KsBuf[cur];
        bf16 *Vs       = VsBuf[cur];
        const unsigned vb = (unsigned)(uintptr_t)Vs;

        *(bf16x8*)&Ks[krow][kcol]       = kr0;
        *(bf16x8*)&Ks[krow][kcol + 8]   = kr1;
        *(bf16x8*)(Vs + tid * 8)        = vr0;
        *(bf16x8*)(Vs + 2048 + tid * 8) = vr1;
        __syncthreads();

        {
            const int jn = (kt + 1 < NT ? kt + 1 : kt) * KVB;
            kr0 = *(const bf16x8*)(kbase + (size_t)(jn + krow) * LD + kcol);
            kr1 = *(const bf16x8*)(kbase + (size_t)(jn + krow) * LD + kcol + 8);
            vr0 = vload(jn, tid * 8);
            vr1 = vload(jn, 2048 + tid * 8);
        }

        f32x16 sT0 = {}, sT1 = {};
        __builtin_amdgcn_s_setprio(1);
        #pragma unroll
        for (int ds = 0; ds < 4; ++ds) {
            bf16x8 kf = *(const bf16x8*)&Ks[l31][ds * 16 + hi_ * 8];
            sT0 = __builtin_amdgcn_mfma_f32_32x32x16_bf16(kf, qf[ds], sT0, 0, 0, 0);
        }
        #pragma unroll
        for (int ds = 0; ds < 4; ++ds) {
            bf16x8 kf = *(const bf16x8*)&Ks[32 + l31][ds * 16 + hi_ * 8];
            sT1 = __builtin_amdgcn_mfma_f32_32x32x16_bf16(kf, qf[ds], sT1, 0, 0, 0);
        }
        __builtin_amdgcn_s_setprio(0);

        float pm = fmaxf(sT0[0], sT0[1]);
        #pragma unroll
        for (int r = 2; r < 16; r += 2) pm = fmaxf(fmaxf(pm, sT0[r]), sT0[r + 1]);
        #pragma unroll
        for (int r = 0; r < 16; r += 2) pm = fmaxf(fmaxf(pm, sT1[r]), sT1[r + 1]);
        pm = fmaxf(pm, __shfl_xor(pm, 32));
        if (!__all(pm <= mrow + THR)) {
            const float mn = fmaxf(mrow, pm);
            const float corr = exp2_fast(mrow - mn);
            mrow = mn;
            lsum *= corr;
            #pragma unroll
            for (int r = 0; r < 16; ++r) { o0[r] *= corr; o1[r] *= corr; }
        }
        #pragma unroll
        for (int r = 0; r < 16; ++r) sT0[r] = exp2_fast(sT0[r] - mrow);
        #pragma unroll
        for (int r = 0; r < 16; ++r) sT1[r] = exp2_fast(sT1[r] - mrow);
        f32x2 ps2 = {0.f, 0.f};
        #pragma unroll
        for (int r = 0; r < 16; r += 2) {
            ps2 += (f32x2){sT0[r], sT0[r + 1]};
            ps2 += (f32x2){sT1[r], sT1[r + 1]};
        }
        float ps = ps2[0] + ps2[1];
        ps += __shfl_xor(ps, 32);
        lsum += ps;

        unsigned w0[8], w1[8];
        #pragma unroll
        for (int j2 = 0; j2 < 8; ++j2) {
            w0[j2] = cvt_pk_bf16(sT0[2 * j2], sT0[2 * j2 + 1]);
            w1[j2] = cvt_pk_bf16(sT1[2 * j2], sT1[2 * j2 + 1]);
        }
        bf16x8 pf[4];
        #pragma unroll
        for (int ks = 0; ks < 4; ++ks) {
            const int jb = 4 * (ks & 1);
            unsigned a0 = (ks >> 1) ? w1[jb]     : w0[jb];
            unsigned b0 = (ks >> 1) ? w1[jb + 2] : w0[jb + 2];
            unsigned a1 = (ks >> 1) ? w1[jb + 1] : w0[jb + 1];
            unsigned b1 = (ks >> 1) ? w1[jb + 3] : w0[jb + 3];
            permlane32_swap(a0, b0);
            permlane32_swap(a1, b1);
            union { bf16x8 f; unsigned w[4]; } u;
            u.w[0] = a0; u.w[1] = a1; u.w[2] = b0; u.w[3] = b1;
            pf[ks] = u.f;
        }

        #pragma unroll
        for (int dt = 0; dt < 2; ++dt) {
            s16x4 t[8];
            #pragma unroll
            for (int ks = 0; ks < 4; ++ks) {
                unsigned a = vb + ks * 2048 + hi_ * 1024 + dt * 256 + g16 * 128 + l16 * 8;
                t[ks * 2]     = ds_tr16(a);
                t[ks * 2 + 1] = ds_tr16(a + 512);
            }
            asm volatile("s_waitcnt lgkmcnt(0)" ::: "memory");
            __builtin_amdgcn_sched_barrier(0);
            __builtin_amdgcn_s_setprio(1);
            #pragma unroll
            for (int ks = 0; ks < 4; ++ks) {
                union { bf16x8 f; s16x4 h[2]; } u;
                u.h[0] = t[ks * 2]; u.h[1] = t[ks * 2 + 1];
                if (dt == 0) o0 = __builtin_amdgcn_mfma_f32_32x32x16_bf16(u.f, pf[ks], o0, 0, 0, 0);
                else         o1 = __builtin_amdgcn_mfma_f32_32x32x16_bf16(u.f, pf[ks], o1, 0, 0, 0);
            }
            __builtin_amdgcn_s_setprio(0);
        }
    }

    bf16 (*Os)[72] = (bf16 (*)[72])&KsBuf[0][0][0];
    const float inv = 1.f / lsum;
    __syncthreads();
    #pragma unroll
    for (int r = 0; r < 16; ++r) {
        const int d0 = (r & 3) + 8 * (r >> 2) + 4 * hi_;
        Os[wv * 32 + l31][d0]      = f2bf(o0[r] * inv);
        Os[wv * 32 + l31][32 + d0] = f2bf(o1[r] * inv);
    }
    __syncthreads();
    {
        const int row = tid >> 1, c0 = (tid & 1) * 32;
        bf16* op = attn_out + (size_t)(b * NSEQ + q0 + row) * DM + h * 64 + c0;
        #pragma unroll
        for (int e = 0; e < 4; ++e)
            *(bf16x8*)(op + e * 8) = *(const bf16x8*)&Os[row][c0 + e * 8];
    }
}

extern "C" void kernel_launch(void* const* d_in, const int* in_sizes, int n_in,
                              void* d_out, int out_size, void* d_ws, size_t ws_size,
                              hipStream_t stream) {
    const float* x     = (const float*)d_in[0];   // [4,2048,1024] fp32
    const float* w_qkv = (const float*)d_in[1];   // [1024,3072]  fp32
    const float* w_out = (const float*)d_in[2];   // [1024,1024]  fp32
    float* out = (float*)d_out;                   // [4,2048,1024] fp32

    bf16* x_bf    = (bf16*)d_out;                 // scratch in d_out
    bf16* qkv     = (bf16*)d_ws;                  // ws[0,48MiB)
    bf16* wqkv_bf = qkv + (size_t)8192 * 3072;    // ws[48,54MiB)
    bf16* attnb   = wqkv_bf;                      // reuse after gemm1
    bf16* wo_bf   = (bf16*)d_ws;                  // reuse after attn

    cvt2_f32_bf16<<<4096 + 1536, 256, 0, stream>>>(
        x, x_bf, 8192 * 1024 / 8, w_qkv, wqkv_bf, 1024 * 3072 / 8);
    gemm_pipe<bf16><<<dim3(3072 / 128, 8192 / 128), 256, 0, stream>>>(
        x_bf, wqkv_bf, qkv, 8192, 3072, 1024);
    attn_mfma32<<<dim3(2048 / 128, 64), 256, 0, stream>>>(qkv, attnb);
    cvt_f32_bf16<<<512, 256, 0, stream>>>(w_out, wo_bf, 1024 * 1024 / 8);
    gemm_pipe<float><<<dim3(1024 / 128, 8192 / 128), 256, 0, stream>>>(
        attnb, wo_bf, out, 8192, 1024, 1024);
}